// Round 1
// baseline (2412.827 us; speedup 1.0000x reference)
//
#include <hip/hip_runtime.h>
#include <hip/hip_bf16.h>

#define NN 50000
#define NE 1600000
#define NIN 256
#define HID 32
#define FOUT 128
#define OSTR 256  // output row stride (concat of two 128-wide outputs)

static constexpr float EPS = 1e-12f;

// ---------------- degree / dinv ----------------
__global__ __launch_bounds__(256) void k_deg(const int* __restrict__ dst,
                                             unsigned* __restrict__ deg, int E) {
    int i = blockIdx.x * 256 + threadIdx.x;
    if (i < E) atomicAdd(&deg[dst[i]], 1u);
}

__global__ __launch_bounds__(256) void k_dinv(const unsigned* __restrict__ deg,
                                              float* __restrict__ dinv, int N) {
    int i = blockIdx.x * 256 + threadIdx.x;
    if (i < N) dinv[i] = rsqrtf((float)(deg[i] + 1u));  // +1 self-loop; always >= 1
}

// ---------------- GEMMs (W staged in LDS) ----------------
// h[N,32] = x[N,256] @ W[256,32]
__global__ __launch_bounds__(256) void k_gemm_in(const float* __restrict__ x,
                                                 const float* __restrict__ W,
                                                 float* __restrict__ h, int N) {
    __shared__ float Ws[NIN * HID];
    for (int i = threadIdx.x; i < NIN * HID; i += 256) Ws[i] = W[i];
    __syncthreads();
    int row = blockIdx.x * 8 + (threadIdx.x >> 5);
    int col = threadIdx.x & 31;
    if (row >= N) return;
    const float4* xr = reinterpret_cast<const float4*>(x + (size_t)row * NIN);
    float acc = 0.f;
#pragma unroll
    for (int k4 = 0; k4 < NIN / 4; ++k4) {
        float4 v = xr[k4];
        int k = k4 * 4;
        acc = fmaf(v.x, Ws[(k + 0) * HID + col], acc);
        acc = fmaf(v.y, Ws[(k + 1) * HID + col], acc);
        acc = fmaf(v.z, Ws[(k + 2) * HID + col], acc);
        acc = fmaf(v.w, Ws[(k + 3) * HID + col], acc);
    }
    h[(size_t)row * HID + col] = acc;
}

// out[N,32] = in[N,32] @ W[32,32]
__global__ __launch_bounds__(256) void k_gemm_hid(const float* __restrict__ in,
                                                  const float* __restrict__ W,
                                                  float* __restrict__ out, int N) {
    __shared__ float Ws[HID * HID];
    for (int i = threadIdx.x; i < HID * HID; i += 256) Ws[i] = W[i];
    __syncthreads();
    int row = blockIdx.x * 8 + (threadIdx.x >> 5);
    int col = threadIdx.x & 31;
    if (row >= N) return;
    const float4* xr = reinterpret_cast<const float4*>(in + (size_t)row * HID);
    float acc = 0.f;
#pragma unroll
    for (int k4 = 0; k4 < HID / 4; ++k4) {
        float4 v = xr[k4];
        int k = k4 * 4;
        acc = fmaf(v.x, Ws[(k + 0) * HID + col], acc);
        acc = fmaf(v.y, Ws[(k + 1) * HID + col], acc);
        acc = fmaf(v.z, Ws[(k + 2) * HID + col], acc);
        acc = fmaf(v.w, Ws[(k + 3) * HID + col], acc);
    }
    out[(size_t)row * HID + col] = acc;
}

// out[N,128] = in[N,32] @ W[32,128]
__global__ __launch_bounds__(256) void k_gemm_out(const float* __restrict__ in,
                                                  const float* __restrict__ W,
                                                  float* __restrict__ out, int N) {
    __shared__ float Ws[HID * FOUT];
    for (int i = threadIdx.x; i < HID * FOUT; i += 256) Ws[i] = W[i];
    __syncthreads();
    int row = blockIdx.x * 2 + (threadIdx.x >> 7);
    int col = threadIdx.x & 127;
    if (row >= N) return;
    const float4* xr = reinterpret_cast<const float4*>(in + (size_t)row * HID);
    float acc = 0.f;
#pragma unroll
    for (int k4 = 0; k4 < HID / 4; ++k4) {
        float4 v = xr[k4];
        int k = k4 * 4;
        acc = fmaf(v.x, Ws[(k + 0) * FOUT + col], acc);
        acc = fmaf(v.y, Ws[(k + 1) * FOUT + col], acc);
        acc = fmaf(v.z, Ws[(k + 2) * FOUT + col], acc);
        acc = fmaf(v.w, Ws[(k + 3) * FOUT + col], acc);
    }
    out[(size_t)row * FOUT + col] = acc;
}

// ---------------- aggregation ----------------
// out[i*S+f] = h[i*F+f] * dinv[i]^2 + b[f]   (self-loop term + bias init)
template <int F, int S>
__global__ __launch_bounds__(256) void k_agg_init(const float* __restrict__ h,
                                                  const float* __restrict__ dinv,
                                                  const float* __restrict__ b,
                                                  float* __restrict__ out, int N) {
    constexpr int LOG = (F == 32) ? 5 : 7;
    int idx = blockIdx.x * 256 + threadIdx.x;
    int i = idx >> LOG;
    int f = idx & (F - 1);
    if (i >= N) return;
    float di = dinv[i];
    out[(size_t)i * S + f] = fmaf(h[(size_t)i * F + f], di * di, b[f]);
}

// per (edge, feature): out[dst*S+f] += h[src*F+f] * dinv[src]*dinv[dst]
template <int F, int S>
__global__ __launch_bounds__(256) void k_agg_edges(const float* __restrict__ h,
                                                   const int* __restrict__ src,
                                                   const int* __restrict__ dst,
                                                   const float* __restrict__ dinv,
                                                   float* __restrict__ out, int E) {
    constexpr int LOG = (F == 32) ? 5 : 7;
    long long idx = (long long)blockIdx.x * 256 + threadIdx.x;
    int e = (int)(idx >> LOG);
    int f = (int)(idx & (F - 1));
    if (e >= E) return;
    int s = src[e], d = dst[e];
    float w = dinv[s] * dinv[d];
    float v = h[(size_t)s * F + f] * w;
    __hip_atomic_fetch_add(&out[(size_t)d * S + f], v, __ATOMIC_RELAXED,
                           __HIP_MEMORY_SCOPE_AGENT);
}

// ---------------- cross-view mixing ----------------
// sim = cos(x1,x2) per row; x1 <- x1 + x2*sim; x2 <- x2 + x1_old*sim
__global__ __launch_bounds__(256) void k_mix(float* __restrict__ x1,
                                             float* __restrict__ x2, int N) {
    int i = blockIdx.x * 256 + threadIdx.x;
    if (i >= N) return;
    float4* a4 = reinterpret_cast<float4*>(x1 + (size_t)i * HID);
    float4* b4 = reinterpret_cast<float4*>(x2 + (size_t)i * HID);
    float4 a[HID / 4], b[HID / 4];
    float n1 = 0.f, n2 = 0.f, dt = 0.f;
#pragma unroll
    for (int j = 0; j < HID / 4; ++j) {
        a[j] = a4[j];
        b[j] = b4[j];
        n1 += a[j].x * a[j].x + a[j].y * a[j].y + a[j].z * a[j].z + a[j].w * a[j].w;
        n2 += b[j].x * b[j].x + b[j].y * b[j].y + b[j].z * b[j].z + b[j].w * b[j].w;
        dt += a[j].x * b[j].x + a[j].y * b[j].y + a[j].z * b[j].z + a[j].w * b[j].w;
    }
    float sim = dt / (fmaxf(sqrtf(n1), EPS) * fmaxf(sqrtf(n2), EPS));
#pragma unroll
    for (int j = 0; j < HID / 4; ++j) {
        float4 m, s;
        m.x = fmaf(b[j].x, sim, a[j].x);
        m.y = fmaf(b[j].y, sim, a[j].y);
        m.z = fmaf(b[j].z, sim, a[j].z);
        m.w = fmaf(b[j].w, sim, a[j].w);
        s.x = fmaf(a[j].x, sim, b[j].x);
        s.y = fmaf(a[j].y, sim, b[j].y);
        s.z = fmaf(a[j].z, sim, b[j].z);
        s.w = fmaf(a[j].w, sim, b[j].w);
        a4[j] = m;
        b4[j] = s;
    }
}

// ---------------- host ----------------
extern "C" void kernel_launch(void* const* d_in, const int* in_sizes, int n_in,
                              void* d_out, int out_size, void* d_ws, size_t ws_size,
                              hipStream_t stream) {
    const float* x     = (const float*)d_in[0];
    const int*   ei_u  = (const int*)d_in[1];   // [2, NE]: src row then dst row
    const int*   ei_u2 = (const int*)d_in[2];
    const float* W_in  = (const float*)d_in[3];
    const float* b_in  = (const float*)d_in[4];
    const float* W_hid = (const float*)d_in[5];
    const float* b_hid = (const float*)d_in[6];
    const float* W_out = (const float*)d_in[7];
    const float* b_out = (const float*)d_in[8];
    float* out = (float*)d_out;

    const int* src_u  = ei_u;
    const int* dst_u  = ei_u + NE;
    const int* src_u2 = ei_u2;
    const int* dst_u2 = ei_u2 + NE;

    // workspace carve-up (all 256B-aligned)
    char* w = (char*)d_ws;
    auto carve = [&](size_t bytes) {
        char* p = w;
        w += (bytes + 255) & ~(size_t)255;
        return p;
    };
    unsigned* deg_u  = (unsigned*)carve(NN * sizeof(unsigned));
    unsigned* deg_u2 = (unsigned*)carve(NN * sizeof(unsigned));
    float* dinv_u  = (float*)carve(NN * sizeof(float));
    float* dinv_u2 = (float*)carve(NN * sizeof(float));
    float* A = (float*)carve((size_t)NN * HID * sizeof(float));
    float* B = (float*)carve((size_t)NN * HID * sizeof(float));
    float* C = (float*)carve((size_t)NN * HID * sizeof(float));
    float* D = (float*)carve((size_t)NN * HID * sizeof(float));
    float* H3 = (float*)carve((size_t)NN * FOUT * sizeof(float));

    const int BLK = 256;
    const int gE   = (NE + BLK - 1) / BLK;       // 6250
    const int gN   = (NN + BLK - 1) / BLK;       // 196
    const int gN32 = (NN * HID) / BLK;           // 6250 (exact)
    const int gE32 = (int)(((long long)NE * HID) / BLK);    // 200000 (exact)
    const int gN128 = (NN * FOUT) / BLK;         // 25000 (exact)
    const int gE128 = (int)(((long long)NE * FOUT) / BLK);  // 800000 (exact)

    // --- degrees & dinv (per view, reused across layers) ---
    hipMemsetAsync(deg_u, 0, 2 * ((NN * sizeof(unsigned) + 255) & ~(size_t)255), stream);
    k_deg<<<gE, BLK, 0, stream>>>(dst_u, deg_u, NE);
    k_deg<<<gE, BLK, 0, stream>>>(dst_u2, deg_u2, NE);
    k_dinv<<<gN, BLK, 0, stream>>>(deg_u, dinv_u, NN);
    k_dinv<<<gN, BLK, 0, stream>>>(deg_u2, dinv_u2, NN);

    // --- layer 1: h = x @ W_in (shared by both views) ---
    k_gemm_in<<<(NN + 7) / 8, BLK, 0, stream>>>(x, W_in, A, NN);
    // view u -> B
    k_agg_init<HID, HID><<<gN32, BLK, 0, stream>>>(A, dinv_u, b_in, B, NN);
    k_agg_edges<HID, HID><<<gE32, BLK, 0, stream>>>(A, src_u, dst_u, dinv_u, B, NE);
    // view u2 -> C
    k_agg_init<HID, HID><<<gN32, BLK, 0, stream>>>(A, dinv_u2, b_in, C, NN);
    k_agg_edges<HID, HID><<<gE32, BLK, 0, stream>>>(A, src_u2, dst_u2, dinv_u2, C, NE);
    // cross mix: B=mian, C=sup
    k_mix<<<gN, BLK, 0, stream>>>(B, C, NN);

    // --- layer 2 ---
    k_gemm_hid<<<(NN + 7) / 8, BLK, 0, stream>>>(B, W_hid, D, NN);  // mian @ W_hid
    k_gemm_hid<<<(NN + 7) / 8, BLK, 0, stream>>>(C, W_hid, A, NN);  // sup  @ W_hid
    k_agg_init<HID, HID><<<gN32, BLK, 0, stream>>>(D, dinv_u, b_hid, B, NN);
    k_agg_edges<HID, HID><<<gE32, BLK, 0, stream>>>(D, src_u, dst_u, dinv_u, B, NE);
    k_agg_init<HID, HID><<<gN32, BLK, 0, stream>>>(A, dinv_u2, b_hid, C, NN);
    k_agg_edges<HID, HID><<<gE32, BLK, 0, stream>>>(A, src_u2, dst_u2, dinv_u2, C, NE);
    k_mix<<<gN, BLK, 0, stream>>>(B, C, NN);

    // --- layer 3: BOTH branches use edge_index_u (and thus dinv_u) ---
    // branch 1 -> out[:, 0:128]
    k_gemm_out<<<(NN + 1) / 2, BLK, 0, stream>>>(B, W_out, H3, NN);
    k_agg_init<FOUT, OSTR><<<gN128, BLK, 0, stream>>>(H3, dinv_u, b_out, out, NN);
    k_agg_edges<FOUT, OSTR><<<gE128, BLK, 0, stream>>>(H3, src_u, dst_u, dinv_u, out, NE);
    // branch 2 -> out[:, 128:256]
    k_gemm_out<<<(NN + 1) / 2, BLK, 0, stream>>>(C, W_out, H3, NN);
    k_agg_init<FOUT, OSTR><<<gN128, BLK, 0, stream>>>(H3, dinv_u, b_out, out + FOUT, NN);
    k_agg_edges<FOUT, OSTR><<<gE128, BLK, 0, stream>>>(H3, src_u, dst_u, dinv_u, out + FOUT, NE);

    (void)in_sizes; (void)n_in; (void)out_size; (void)ws_size;
}

// Round 2
// 895.593 us; speedup vs baseline: 2.6941x; 2.6941x over previous
//
#include <hip/hip_runtime.h>
#include <hip/hip_bf16.h>

#define NN 50000
#define NE 1600000
#define NIN 256
#define HID 32
#define FOUT 128
#define OSTR 256

static constexpr float EPS = 1e-12f;

// ---------------- degree / dinv ----------------
__global__ __launch_bounds__(256) void k_deg(const int* __restrict__ dst,
                                             unsigned* __restrict__ deg, int E) {
    int i = blockIdx.x * 256 + threadIdx.x;
    if (i < E) atomicAdd(&deg[dst[i]], 1u);
}

__global__ __launch_bounds__(256) void k_dinv(const unsigned* __restrict__ deg,
                                              float* __restrict__ dinv, int N) {
    int i = blockIdx.x * 256 + threadIdx.x;
    if (i < N) dinv[i] = rsqrtf((float)(deg[i] + 1u));
}

// ---------------- exclusive scan (3-kernel hierarchical) ----------------
__global__ __launch_bounds__(256) void k_scan1(const unsigned* __restrict__ deg,
                                               int* __restrict__ out,
                                               unsigned* __restrict__ bsum, int N) {
    __shared__ unsigned tmp[256];
    int i = blockIdx.x * 256 + threadIdx.x;
    unsigned v = (i < N) ? deg[i] : 0u;
    tmp[threadIdx.x] = v;
    __syncthreads();
    for (int off = 1; off < 256; off <<= 1) {
        unsigned t = (threadIdx.x >= (unsigned)off) ? tmp[threadIdx.x - off] : 0u;
        __syncthreads();
        tmp[threadIdx.x] += t;
        __syncthreads();
    }
    if (i < N) out[i] = (int)(tmp[threadIdx.x] - v);
    if (threadIdx.x == 255) bsum[blockIdx.x] = tmp[255];
}

__global__ __launch_bounds__(256) void k_scan2(unsigned* __restrict__ bsum, int NB) {
    __shared__ unsigned tmp[256];
    unsigned v = (threadIdx.x < (unsigned)NB) ? bsum[threadIdx.x] : 0u;
    tmp[threadIdx.x] = v;
    __syncthreads();
    for (int off = 1; off < 256; off <<= 1) {
        unsigned t = (threadIdx.x >= (unsigned)off) ? tmp[threadIdx.x - off] : 0u;
        __syncthreads();
        tmp[threadIdx.x] += t;
        __syncthreads();
    }
    if (threadIdx.x < (unsigned)NB) bsum[threadIdx.x] = tmp[threadIdx.x] - v;
}

__global__ __launch_bounds__(256) void k_scan3(int* __restrict__ out,
                                               const unsigned* __restrict__ bsum, int N) {
    int i = blockIdx.x * 256 + threadIdx.x;
    if (i < N) out[i] += (int)bsum[blockIdx.x];
}

// ---------------- CSR scatter ----------------
__global__ __launch_bounds__(256) void k_scatter(const int* __restrict__ src,
                                                 const int* __restrict__ dst,
                                                 const int* __restrict__ rowptr,
                                                 unsigned* __restrict__ cursor,
                                                 int* __restrict__ csr, int E) {
    int e = blockIdx.x * 256 + threadIdx.x;
    if (e < E) {
        int d = dst[e];
        unsigned p = atomicAdd(&cursor[d], 1u);
        csr[rowptr[d] + (int)p] = src[e];
    }
}

// ---------------- GEMMs (W staged in LDS; optional row scale by dinv) ----------------
__global__ __launch_bounds__(256) void k_gemm_in(const float* __restrict__ x,
                                                 const float* __restrict__ W,
                                                 float* __restrict__ h, int N) {
    __shared__ float Ws[NIN * HID];
    for (int i = threadIdx.x; i < NIN * HID; i += 256) Ws[i] = W[i];
    __syncthreads();
    int row = blockIdx.x * 8 + (threadIdx.x >> 5);
    int col = threadIdx.x & 31;
    if (row >= N) return;
    const float4* xr = reinterpret_cast<const float4*>(x + (size_t)row * NIN);
    float acc = 0.f;
#pragma unroll
    for (int k4 = 0; k4 < NIN / 4; ++k4) {
        float4 v = xr[k4];
        int k = k4 * 4;
        acc = fmaf(v.x, Ws[(k + 0) * HID + col], acc);
        acc = fmaf(v.y, Ws[(k + 1) * HID + col], acc);
        acc = fmaf(v.z, Ws[(k + 2) * HID + col], acc);
        acc = fmaf(v.w, Ws[(k + 3) * HID + col], acc);
    }
    h[(size_t)row * HID + col] = acc;
}

// out[N,32] = (in[N,32] @ W[32,32]) * dinv[row]
__global__ __launch_bounds__(256) void k_gemm_hid(const float* __restrict__ in,
                                                  const float* __restrict__ W,
                                                  const float* __restrict__ dinv,
                                                  float* __restrict__ out, int N) {
    __shared__ float Ws[HID * HID];
    for (int i = threadIdx.x; i < HID * HID; i += 256) Ws[i] = W[i];
    __syncthreads();
    int row = blockIdx.x * 8 + (threadIdx.x >> 5);
    int col = threadIdx.x & 31;
    if (row >= N) return;
    const float4* xr = reinterpret_cast<const float4*>(in + (size_t)row * HID);
    float acc = 0.f;
#pragma unroll
    for (int k4 = 0; k4 < HID / 4; ++k4) {
        float4 v = xr[k4];
        int k = k4 * 4;
        acc = fmaf(v.x, Ws[(k + 0) * HID + col], acc);
        acc = fmaf(v.y, Ws[(k + 1) * HID + col], acc);
        acc = fmaf(v.z, Ws[(k + 2) * HID + col], acc);
        acc = fmaf(v.w, Ws[(k + 3) * HID + col], acc);
    }
    out[(size_t)row * HID + col] = acc * dinv[row];
}

// out[N,128] = (in[N,32] @ W[32,128]) * dinv[row]
__global__ __launch_bounds__(256) void k_gemm_out(const float* __restrict__ in,
                                                  const float* __restrict__ W,
                                                  const float* __restrict__ dinv,
                                                  float* __restrict__ out, int N) {
    __shared__ float Ws[HID * FOUT];
    for (int i = threadIdx.x; i < HID * FOUT; i += 256) Ws[i] = W[i];
    __syncthreads();
    int row = blockIdx.x * 2 + (threadIdx.x >> 7);
    int col = threadIdx.x & 127;
    if (row >= N) return;
    const float4* xr = reinterpret_cast<const float4*>(in + (size_t)row * HID);
    float acc = 0.f;
#pragma unroll
    for (int k4 = 0; k4 < HID / 4; ++k4) {
        float4 v = xr[k4];
        int k = k4 * 4;
        acc = fmaf(v.x, Ws[(k + 0) * FOUT + col], acc);
        acc = fmaf(v.y, Ws[(k + 1) * FOUT + col], acc);
        acc = fmaf(v.z, Ws[(k + 2) * FOUT + col], acc);
        acc = fmaf(v.w, Ws[(k + 3) * FOUT + col], acc);
    }
    out[(size_t)row * FOUT + col] = acc * dinv[row];
}

// ---------------- layer-1 scale: two views from one h ----------------
__global__ __launch_bounds__(256) void k_scale2(const float* __restrict__ h,
                                                const float* __restrict__ d1,
                                                const float* __restrict__ d2,
                                                float* __restrict__ o1,
                                                float* __restrict__ o2, int N) {
    int idx = blockIdx.x * 256 + threadIdx.x;
    int i = idx >> 5;
    if (i >= N) return;
    float v = h[idx];
    o1[idx] = v * d1[i];
    o2[idx] = v * d2[i];
}

// ---------------- pull aggregation ----------------
// hs rows already scaled by dinv[src]. out[d] = dinv[d]*(hs[d] + sum_e hs[csr[e]]) + b
template <int F, int S>
__global__ __launch_bounds__(256) void k_pull(const float* __restrict__ hs,
                                              const int* __restrict__ csr,
                                              const int* __restrict__ rowptr,
                                              const unsigned* __restrict__ deg,
                                              const float* __restrict__ dinv,
                                              const float* __restrict__ b,
                                              float* __restrict__ out, int N) {
    constexpr int NPB = 256 / F;
    int node = blockIdx.x * NPB + threadIdx.x / F;
    int f = threadIdx.x % F;
    if (node >= N) return;
    int beg = rowptr[node];
    int end = beg + (int)deg[node];
    float acc = hs[(size_t)node * F + f];  // self-loop term
    int e = beg;
    for (; e + 4 <= end; e += 4) {
        int s0 = csr[e + 0];
        int s1 = csr[e + 1];
        int s2 = csr[e + 2];
        int s3 = csr[e + 3];
        float v0 = hs[(size_t)s0 * F + f];
        float v1 = hs[(size_t)s1 * F + f];
        float v2 = hs[(size_t)s2 * F + f];
        float v3 = hs[(size_t)s3 * F + f];
        acc += v0 + v1 + v2 + v3;
    }
    for (; e < end; ++e) acc += hs[(size_t)csr[e] * F + f];
    out[(size_t)node * S + f] = fmaf(acc, dinv[node], b[f]);
}

// ---------------- cross-view mixing ----------------
__global__ __launch_bounds__(256) void k_mix(float* __restrict__ x1,
                                             float* __restrict__ x2, int N) {
    int i = blockIdx.x * 256 + threadIdx.x;
    if (i >= N) return;
    float4* a4 = reinterpret_cast<float4*>(x1 + (size_t)i * HID);
    float4* b4 = reinterpret_cast<float4*>(x2 + (size_t)i * HID);
    float4 a[HID / 4], b[HID / 4];
    float n1 = 0.f, n2 = 0.f, dt = 0.f;
#pragma unroll
    for (int j = 0; j < HID / 4; ++j) {
        a[j] = a4[j];
        b[j] = b4[j];
        n1 += a[j].x * a[j].x + a[j].y * a[j].y + a[j].z * a[j].z + a[j].w * a[j].w;
        n2 += b[j].x * b[j].x + b[j].y * b[j].y + b[j].z * b[j].z + b[j].w * b[j].w;
        dt += a[j].x * b[j].x + a[j].y * b[j].y + a[j].z * b[j].z + a[j].w * b[j].w;
    }
    float sim = dt / (fmaxf(sqrtf(n1), EPS) * fmaxf(sqrtf(n2), EPS));
#pragma unroll
    for (int j = 0; j < HID / 4; ++j) {
        float4 m, s;
        m.x = fmaf(b[j].x, sim, a[j].x);
        m.y = fmaf(b[j].y, sim, a[j].y);
        m.z = fmaf(b[j].z, sim, a[j].z);
        m.w = fmaf(b[j].w, sim, a[j].w);
        s.x = fmaf(a[j].x, sim, b[j].x);
        s.y = fmaf(a[j].y, sim, b[j].y);
        s.z = fmaf(a[j].z, sim, b[j].z);
        s.w = fmaf(a[j].w, sim, b[j].w);
        a4[j] = m;
        b4[j] = s;
    }
}

// ---------------- host ----------------
extern "C" void kernel_launch(void* const* d_in, const int* in_sizes, int n_in,
                              void* d_out, int out_size, void* d_ws, size_t ws_size,
                              hipStream_t stream) {
    const float* x     = (const float*)d_in[0];
    const int*   ei_u  = (const int*)d_in[1];
    const int*   ei_u2 = (const int*)d_in[2];
    const float* W_in  = (const float*)d_in[3];
    const float* b_in  = (const float*)d_in[4];
    const float* W_hid = (const float*)d_in[5];
    const float* b_hid = (const float*)d_in[6];
    const float* W_out = (const float*)d_in[7];
    const float* b_out = (const float*)d_in[8];
    float* out = (float*)d_out;

    const int* src_u  = ei_u;
    const int* dst_u  = ei_u + NE;
    const int* src_u2 = ei_u2;
    const int* dst_u2 = ei_u2 + NE;

    char* w = (char*)d_ws;
    auto carve = [&](size_t bytes) {
        char* p = w;
        w += (bytes + 255) & ~(size_t)255;
        return p;
    };
    unsigned* deg_u   = (unsigned*)carve(NN * sizeof(unsigned));
    unsigned* deg_u2  = (unsigned*)carve(NN * sizeof(unsigned));
    float*    dinv_u  = (float*)carve(NN * sizeof(float));
    float*    dinv_u2 = (float*)carve(NN * sizeof(float));
    int*      rp_u    = (int*)carve(NN * sizeof(int));
    int*      rp_u2   = (int*)carve(NN * sizeof(int));
    unsigned* cursor  = (unsigned*)carve(NN * sizeof(unsigned));
    unsigned* bsum    = (unsigned*)carve(256 * sizeof(unsigned));
    int*      csr_u   = (int*)carve((size_t)NE * sizeof(int));
    int*      csr_u2  = (int*)carve((size_t)NE * sizeof(int));
    float* A = (float*)carve((size_t)NN * HID * sizeof(float));
    float* B = (float*)carve((size_t)NN * HID * sizeof(float));
    float* C = (float*)carve((size_t)NN * HID * sizeof(float));
    float* D = (float*)carve((size_t)NN * HID * sizeof(float));
    float* E = (float*)carve((size_t)NN * HID * sizeof(float));
    float* H3 = (float*)carve((size_t)NN * FOUT * sizeof(float));

    const int BLK = 256;
    const int gE  = (NE + BLK - 1) / BLK;   // 6250
    const int gN  = (NN + BLK - 1) / BLK;   // 196
    const int gN32 = (NN * HID) / BLK;      // 6250 exact
    const int gP32 = (NN + 7) / 8;          // pull F=32: 8 nodes/block
    const int gP128 = (NN + 1) / 2;         // pull F=128: 2 nodes/block

    // degrees & dinv
    hipMemsetAsync(deg_u, 0, 2 * ((NN * sizeof(unsigned) + 255) & ~(size_t)255), stream);
    k_deg<<<gE, BLK, 0, stream>>>(dst_u, deg_u, NE);
    k_deg<<<gE, BLK, 0, stream>>>(dst_u2, deg_u2, NE);
    k_dinv<<<gN, BLK, 0, stream>>>(deg_u, dinv_u, NN);
    k_dinv<<<gN, BLK, 0, stream>>>(deg_u2, dinv_u2, NN);

    // CSR view u
    k_scan1<<<gN, BLK, 0, stream>>>(deg_u, rp_u, bsum, NN);
    k_scan2<<<1, BLK, 0, stream>>>(bsum, gN);
    k_scan3<<<gN, BLK, 0, stream>>>(rp_u, bsum, NN);
    hipMemsetAsync(cursor, 0, NN * sizeof(unsigned), stream);
    k_scatter<<<gE, BLK, 0, stream>>>(src_u, dst_u, rp_u, cursor, csr_u, NE);
    // CSR view u2
    k_scan1<<<gN, BLK, 0, stream>>>(deg_u2, rp_u2, bsum, NN);
    k_scan2<<<1, BLK, 0, stream>>>(bsum, gN);
    k_scan3<<<gN, BLK, 0, stream>>>(rp_u2, bsum, NN);
    hipMemsetAsync(cursor, 0, NN * sizeof(unsigned), stream);
    k_scatter<<<gE, BLK, 0, stream>>>(src_u2, dst_u2, rp_u2, cursor, csr_u2, NE);

    // --- layer 1 ---
    k_gemm_in<<<(NN + 7) / 8, BLK, 0, stream>>>(x, W_in, A, NN);
    k_scale2<<<gN32, BLK, 0, stream>>>(A, dinv_u, dinv_u2, B, D, NN);
    k_pull<HID, HID><<<gP32, BLK, 0, stream>>>(B, csr_u, rp_u, deg_u, dinv_u, b_in, C, NN);
    k_pull<HID, HID><<<gP32, BLK, 0, stream>>>(D, csr_u2, rp_u2, deg_u2, dinv_u2, b_in, E, NN);
    k_mix<<<gN, BLK, 0, stream>>>(C, E, NN);

    // --- layer 2 ---
    k_gemm_hid<<<(NN + 7) / 8, BLK, 0, stream>>>(C, W_hid, dinv_u, A, NN);
    k_gemm_hid<<<(NN + 7) / 8, BLK, 0, stream>>>(E, W_hid, dinv_u2, B, NN);
    k_pull<HID, HID><<<gP32, BLK, 0, stream>>>(A, csr_u, rp_u, deg_u, dinv_u, b_hid, C, NN);
    k_pull<HID, HID><<<gP32, BLK, 0, stream>>>(B, csr_u2, rp_u2, deg_u2, dinv_u2, b_hid, E, NN);
    k_mix<<<gN, BLK, 0, stream>>>(C, E, NN);

    // --- layer 3: both branches use view u ---
    k_gemm_out<<<gP128, BLK, 0, stream>>>(C, W_out, dinv_u, H3, NN);
    k_pull<FOUT, OSTR><<<gP128, BLK, 0, stream>>>(H3, csr_u, rp_u, deg_u, dinv_u, b_out, out, NN);
    k_gemm_out<<<gP128, BLK, 0, stream>>>(E, W_out, dinv_u, H3, NN);
    k_pull<FOUT, OSTR><<<gP128, BLK, 0, stream>>>(H3, csr_u, rp_u, deg_u, dinv_u, b_out, out + FOUT, NN);

    (void)in_sizes; (void)n_in; (void)out_size; (void)ws_size;
}

// Round 3
// 659.745 us; speedup vs baseline: 3.6572x; 1.3575x over previous
//
#include <hip/hip_runtime.h>
#include <hip/hip_bf16.h>

#define NN 50000
#define NE 1600000
#define NIN 256
#define HID 32
#define FOUT 128
#define OSTR 256

static constexpr float EPS = 1e-12f;

// ---------------- degree / dinv ----------------
__global__ __launch_bounds__(256) void k_deg(const int* __restrict__ dst,
                                             unsigned* __restrict__ deg, int E) {
    int i = blockIdx.x * 256 + threadIdx.x;
    if (i < E) atomicAdd(&deg[dst[i]], 1u);
}

__global__ __launch_bounds__(256) void k_dinv(const unsigned* __restrict__ deg,
                                              float* __restrict__ dinv, int N) {
    int i = blockIdx.x * 256 + threadIdx.x;
    if (i < N) dinv[i] = rsqrtf((float)(deg[i] + 1u));
}

// ---------------- exclusive scan (3-kernel hierarchical) ----------------
__global__ __launch_bounds__(256) void k_scan1(const unsigned* __restrict__ deg,
                                               int* __restrict__ out,
                                               unsigned* __restrict__ bsum, int N) {
    __shared__ unsigned tmp[256];
    int i = blockIdx.x * 256 + threadIdx.x;
    unsigned v = (i < N) ? deg[i] : 0u;
    tmp[threadIdx.x] = v;
    __syncthreads();
    for (int off = 1; off < 256; off <<= 1) {
        unsigned t = (threadIdx.x >= (unsigned)off) ? tmp[threadIdx.x - off] : 0u;
        __syncthreads();
        tmp[threadIdx.x] += t;
        __syncthreads();
    }
    if (i < N) out[i] = (int)(tmp[threadIdx.x] - v);
    if (threadIdx.x == 255) bsum[blockIdx.x] = tmp[255];
}

__global__ __launch_bounds__(256) void k_scan2(unsigned* __restrict__ bsum, int NB) {
    __shared__ unsigned tmp[256];
    unsigned v = (threadIdx.x < (unsigned)NB) ? bsum[threadIdx.x] : 0u;
    tmp[threadIdx.x] = v;
    __syncthreads();
    for (int off = 1; off < 256; off <<= 1) {
        unsigned t = (threadIdx.x >= (unsigned)off) ? tmp[threadIdx.x - off] : 0u;
        __syncthreads();
        tmp[threadIdx.x] += t;
        __syncthreads();
    }
    if (threadIdx.x < (unsigned)NB) bsum[threadIdx.x] = tmp[threadIdx.x] - v;
}

__global__ __launch_bounds__(256) void k_scan3(int* __restrict__ out,
                                               const unsigned* __restrict__ bsum, int N) {
    int i = blockIdx.x * 256 + threadIdx.x;
    if (i < N) out[i] += (int)bsum[blockIdx.x];
}

// ---------------- CSR scatter ----------------
__global__ __launch_bounds__(256) void k_scatter(const int* __restrict__ src,
                                                 const int* __restrict__ dst,
                                                 const int* __restrict__ rowptr,
                                                 unsigned* __restrict__ cursor,
                                                 int* __restrict__ csr, int E) {
    int e = blockIdx.x * 256 + threadIdx.x;
    if (e < E) {
        int d = dst[e];
        unsigned p = atomicAdd(&cursor[d], 1u);
        csr[rowptr[d] + (int)p] = src[e];
    }
}

// ---------------- GEMMs (W staged in LDS; optional row scale by dinv) ----------------
__global__ __launch_bounds__(256) void k_gemm_in(const float* __restrict__ x,
                                                 const float* __restrict__ W,
                                                 float* __restrict__ h, int N) {
    __shared__ float Ws[NIN * HID];
    for (int i = threadIdx.x; i < NIN * HID; i += 256) Ws[i] = W[i];
    __syncthreads();
    int row = blockIdx.x * 8 + (threadIdx.x >> 5);
    int col = threadIdx.x & 31;
    if (row >= N) return;
    const float4* xr = reinterpret_cast<const float4*>(x + (size_t)row * NIN);
    float acc = 0.f;
#pragma unroll
    for (int k4 = 0; k4 < NIN / 4; ++k4) {
        float4 v = xr[k4];
        int k = k4 * 4;
        acc = fmaf(v.x, Ws[(k + 0) * HID + col], acc);
        acc = fmaf(v.y, Ws[(k + 1) * HID + col], acc);
        acc = fmaf(v.z, Ws[(k + 2) * HID + col], acc);
        acc = fmaf(v.w, Ws[(k + 3) * HID + col], acc);
    }
    h[(size_t)row * HID + col] = acc;
}

// out[N,32] = (in[N,32] @ W[32,32]) * dinv[row]
__global__ __launch_bounds__(256) void k_gemm_hid(const float* __restrict__ in,
                                                  const float* __restrict__ W,
                                                  const float* __restrict__ dinv,
                                                  float* __restrict__ out, int N) {
    __shared__ float Ws[HID * HID];
    for (int i = threadIdx.x; i < HID * HID; i += 256) Ws[i] = W[i];
    __syncthreads();
    int row = blockIdx.x * 8 + (threadIdx.x >> 5);
    int col = threadIdx.x & 31;
    if (row >= N) return;
    const float4* xr = reinterpret_cast<const float4*>(in + (size_t)row * HID);
    float acc = 0.f;
#pragma unroll
    for (int k4 = 0; k4 < HID / 4; ++k4) {
        float4 v = xr[k4];
        int k = k4 * 4;
        acc = fmaf(v.x, Ws[(k + 0) * HID + col], acc);
        acc = fmaf(v.y, Ws[(k + 1) * HID + col], acc);
        acc = fmaf(v.z, Ws[(k + 2) * HID + col], acc);
        acc = fmaf(v.w, Ws[(k + 3) * HID + col], acc);
    }
    out[(size_t)row * HID + col] = acc * dinv[row];
}

// out[row, 0:128] = Q[row, 0:32] @ W + b ; out[row, 128:256] = Q[row, 32:64] @ W + b
__global__ __launch_bounds__(256) void k_gemm_out2(const float* __restrict__ Q,
                                                   const float* __restrict__ W,
                                                   const float* __restrict__ b,
                                                   float* __restrict__ out, int N) {
    __shared__ float Ws[HID * FOUT];
    for (int i = threadIdx.x; i < HID * FOUT; i += 256) Ws[i] = W[i];
    __syncthreads();
    int row = blockIdx.x * 2 + (threadIdx.x >> 7);
    int col = threadIdx.x & 127;
    if (row >= N) return;
    const float4* q4 = reinterpret_cast<const float4*>(Q + (size_t)row * 64);
    float acc1 = 0.f, acc2 = 0.f;
#pragma unroll
    for (int k4 = 0; k4 < HID / 4; ++k4) {
        float4 v1 = q4[k4];
        float4 v2 = q4[k4 + 8];
        int k = k4 * 4;
        acc1 = fmaf(v1.x, Ws[(k + 0) * FOUT + col], acc1);
        acc1 = fmaf(v1.y, Ws[(k + 1) * FOUT + col], acc1);
        acc1 = fmaf(v1.z, Ws[(k + 2) * FOUT + col], acc1);
        acc1 = fmaf(v1.w, Ws[(k + 3) * FOUT + col], acc1);
        acc2 = fmaf(v2.x, Ws[(k + 0) * FOUT + col], acc2);
        acc2 = fmaf(v2.y, Ws[(k + 1) * FOUT + col], acc2);
        acc2 = fmaf(v2.z, Ws[(k + 2) * FOUT + col], acc2);
        acc2 = fmaf(v2.w, Ws[(k + 3) * FOUT + col], acc2);
    }
    float bb = b[col];
    out[(size_t)row * OSTR + col] = acc1 + bb;
    out[(size_t)row * OSTR + FOUT + col] = acc2 + bb;
}

// ---------------- layer-1 scale: two views from one h ----------------
__global__ __launch_bounds__(256) void k_scale2(const float* __restrict__ h,
                                                const float* __restrict__ d1,
                                                const float* __restrict__ d2,
                                                float* __restrict__ o1,
                                                float* __restrict__ o2, int N) {
    int idx = blockIdx.x * 256 + threadIdx.x;
    int i = idx >> 5;
    if (i >= N) return;
    float v = h[idx];
    o1[idx] = v * d1[i];
    o2[idx] = v * d2[i];
}

// ---------------- pull aggregation (float4 gather) ----------------
// hs rows pre-scaled by dinv[src]. out[d] = dinv[d]*(hs[d] + sum hs[csr[e]]) (+ b)
template <int F, int S, bool BIAS>
__global__ __launch_bounds__(256) void k_pullv(const float* __restrict__ hs,
                                               const int* __restrict__ csr,
                                               const int* __restrict__ rowptr,
                                               const unsigned* __restrict__ deg,
                                               const float* __restrict__ dinv,
                                               const float* __restrict__ b,
                                               float* __restrict__ out, int N) {
    constexpr int L = F / 4;             // lanes per node
    int node = blockIdx.x * (256 / L) + threadIdx.x / L;
    int q = threadIdx.x % L;             // float4 slot within row
    if (node >= N) return;
    const float4* h4 = reinterpret_cast<const float4*>(hs);
    int beg = rowptr[node];
    int end = beg + (int)deg[node];
    float4 acc = h4[(size_t)node * L + q];   // self-loop term
    int e = beg;
    for (; e + 2 <= end; e += 2) {
        int s0 = csr[e];
        int s1 = csr[e + 1];
        float4 v0 = h4[(size_t)s0 * L + q];
        float4 v1 = h4[(size_t)s1 * L + q];
        acc.x += v0.x + v1.x;
        acc.y += v0.y + v1.y;
        acc.z += v0.z + v1.z;
        acc.w += v0.w + v1.w;
    }
    if (e < end) {
        float4 v = h4[(size_t)csr[e] * L + q];
        acc.x += v.x; acc.y += v.y; acc.z += v.z; acc.w += v.w;
    }
    float di = dinv[node];
    float4 r;
    r.x = acc.x * di; r.y = acc.y * di; r.z = acc.z * di; r.w = acc.w * di;
    if (BIAS) {
        r.x += b[q * 4 + 0]; r.y += b[q * 4 + 1];
        r.z += b[q * 4 + 2]; r.w += b[q * 4 + 3];
    }
    *reinterpret_cast<float4*>(out + (size_t)node * S + q * 4) = r;
}

// ---------------- cross-view mixing ----------------
__global__ __launch_bounds__(256) void k_mix(float* __restrict__ x1,
                                             float* __restrict__ x2, int N) {
    int i = blockIdx.x * 256 + threadIdx.x;
    if (i >= N) return;
    float4* a4 = reinterpret_cast<float4*>(x1 + (size_t)i * HID);
    float4* b4 = reinterpret_cast<float4*>(x2 + (size_t)i * HID);
    float4 a[HID / 4], b[HID / 4];
    float n1 = 0.f, n2 = 0.f, dt = 0.f;
#pragma unroll
    for (int j = 0; j < HID / 4; ++j) {
        a[j] = a4[j];
        b[j] = b4[j];
        n1 += a[j].x * a[j].x + a[j].y * a[j].y + a[j].z * a[j].z + a[j].w * a[j].w;
        n2 += b[j].x * b[j].x + b[j].y * b[j].y + b[j].z * b[j].z + b[j].w * b[j].w;
        dt += a[j].x * b[j].x + a[j].y * b[j].y + a[j].z * b[j].z + a[j].w * b[j].w;
    }
    float sim = dt / (fmaxf(sqrtf(n1), EPS) * fmaxf(sqrtf(n2), EPS));
#pragma unroll
    for (int j = 0; j < HID / 4; ++j) {
        float4 m, s;
        m.x = fmaf(b[j].x, sim, a[j].x);
        m.y = fmaf(b[j].y, sim, a[j].y);
        m.z = fmaf(b[j].z, sim, a[j].z);
        m.w = fmaf(b[j].w, sim, a[j].w);
        s.x = fmaf(a[j].x, sim, b[j].x);
        s.y = fmaf(a[j].y, sim, b[j].y);
        s.z = fmaf(a[j].z, sim, b[j].z);
        s.w = fmaf(a[j].w, sim, b[j].w);
        a4[j] = m;
        b4[j] = s;
    }
}

// mix + pack for layer 3: P[i] = [(x1+x2*sim)*dinv_u[i] | (x2+x1*sim)*dinv_u[i]]
__global__ __launch_bounds__(256) void k_mix_pack(const float* __restrict__ x1,
                                                  const float* __restrict__ x2,
                                                  const float* __restrict__ dinv,
                                                  float* __restrict__ P, int N) {
    int i = blockIdx.x * 256 + threadIdx.x;
    if (i >= N) return;
    const float4* a4 = reinterpret_cast<const float4*>(x1 + (size_t)i * HID);
    const float4* b4 = reinterpret_cast<const float4*>(x2 + (size_t)i * HID);
    float4* p4 = reinterpret_cast<float4*>(P + (size_t)i * 64);
    float4 a[HID / 4], b[HID / 4];
    float n1 = 0.f, n2 = 0.f, dt = 0.f;
#pragma unroll
    for (int j = 0; j < HID / 4; ++j) {
        a[j] = a4[j];
        b[j] = b4[j];
        n1 += a[j].x * a[j].x + a[j].y * a[j].y + a[j].z * a[j].z + a[j].w * a[j].w;
        n2 += b[j].x * b[j].x + b[j].y * b[j].y + b[j].z * b[j].z + b[j].w * b[j].w;
        dt += a[j].x * b[j].x + a[j].y * b[j].y + a[j].z * b[j].z + a[j].w * b[j].w;
    }
    float sim = dt / (fmaxf(sqrtf(n1), EPS) * fmaxf(sqrtf(n2), EPS));
    float di = dinv[i];
#pragma unroll
    for (int j = 0; j < HID / 4; ++j) {
        float4 m, s;
        m.x = fmaf(b[j].x, sim, a[j].x) * di;
        m.y = fmaf(b[j].y, sim, a[j].y) * di;
        m.z = fmaf(b[j].z, sim, a[j].z) * di;
        m.w = fmaf(b[j].w, sim, a[j].w) * di;
        s.x = fmaf(a[j].x, sim, b[j].x) * di;
        s.y = fmaf(a[j].y, sim, b[j].y) * di;
        s.z = fmaf(a[j].z, sim, b[j].z) * di;
        s.w = fmaf(a[j].w, sim, b[j].w) * di;
        p4[j] = m;
        p4[j + 8] = s;
    }
}

// ---------------- host ----------------
extern "C" void kernel_launch(void* const* d_in, const int* in_sizes, int n_in,
                              void* d_out, int out_size, void* d_ws, size_t ws_size,
                              hipStream_t stream) {
    const float* x     = (const float*)d_in[0];
    const int*   ei_u  = (const int*)d_in[1];
    const int*   ei_u2 = (const int*)d_in[2];
    const float* W_in  = (const float*)d_in[3];
    const float* b_in  = (const float*)d_in[4];
    const float* W_hid = (const float*)d_in[5];
    const float* b_hid = (const float*)d_in[6];
    const float* W_out = (const float*)d_in[7];
    const float* b_out = (const float*)d_in[8];
    float* out = (float*)d_out;

    const int* src_u  = ei_u;
    const int* dst_u  = ei_u + NE;
    const int* src_u2 = ei_u2;
    const int* dst_u2 = ei_u2 + NE;

    char* w = (char*)d_ws;
    auto carve = [&](size_t bytes) {
        char* p = w;
        w += (bytes + 255) & ~(size_t)255;
        return p;
    };
    unsigned* deg_u   = (unsigned*)carve(NN * sizeof(unsigned));
    unsigned* deg_u2  = (unsigned*)carve(NN * sizeof(unsigned));
    float*    dinv_u  = (float*)carve(NN * sizeof(float));
    float*    dinv_u2 = (float*)carve(NN * sizeof(float));
    int*      rp_u    = (int*)carve(NN * sizeof(int));
    int*      rp_u2   = (int*)carve(NN * sizeof(int));
    unsigned* cursor  = (unsigned*)carve(NN * sizeof(unsigned));
    unsigned* bsum    = (unsigned*)carve(256 * sizeof(unsigned));
    int*      csr_u   = (int*)carve((size_t)NE * sizeof(int));
    int*      csr_u2  = (int*)carve((size_t)NE * sizeof(int));
    float* A = (float*)carve((size_t)NN * HID * sizeof(float));
    float* B = (float*)carve((size_t)NN * HID * sizeof(float));
    float* C = (float*)carve((size_t)NN * HID * sizeof(float));
    float* D = (float*)carve((size_t)NN * HID * sizeof(float));
    float* Ebuf = (float*)carve((size_t)NN * HID * sizeof(float));
    float* P = (float*)carve((size_t)NN * 64 * sizeof(float));
    float* Q = (float*)carve((size_t)NN * 64 * sizeof(float));

    const int BLK = 256;
    const int gE  = (NE + BLK - 1) / BLK;    // 6250
    const int gN  = (NN + BLK - 1) / BLK;    // 196
    const int gN32 = (NN * HID) / BLK;       // 6250 exact
    const int gP32 = (NN + 31) / 32;         // pullv F=32: 32 nodes/block
    const int gP64 = (NN + 15) / 16;         // pullv F=64: 16 nodes/block
    const int gG   = (NN + 7) / 8;
    const int gG2  = (NN + 1) / 2;

    // degrees & dinv
    hipMemsetAsync(deg_u, 0, 2 * ((NN * sizeof(unsigned) + 255) & ~(size_t)255), stream);
    k_deg<<<gE, BLK, 0, stream>>>(dst_u, deg_u, NE);
    k_deg<<<gE, BLK, 0, stream>>>(dst_u2, deg_u2, NE);
    k_dinv<<<gN, BLK, 0, stream>>>(deg_u, dinv_u, NN);
    k_dinv<<<gN, BLK, 0, stream>>>(deg_u2, dinv_u2, NN);

    // CSR view u
    k_scan1<<<gN, BLK, 0, stream>>>(deg_u, rp_u, bsum, NN);
    k_scan2<<<1, BLK, 0, stream>>>(bsum, gN);
    k_scan3<<<gN, BLK, 0, stream>>>(rp_u, bsum, NN);
    hipMemsetAsync(cursor, 0, NN * sizeof(unsigned), stream);
    k_scatter<<<gE, BLK, 0, stream>>>(src_u, dst_u, rp_u, cursor, csr_u, NE);
    // CSR view u2
    k_scan1<<<gN, BLK, 0, stream>>>(deg_u2, rp_u2, bsum, NN);
    k_scan2<<<1, BLK, 0, stream>>>(bsum, gN);
    k_scan3<<<gN, BLK, 0, stream>>>(rp_u2, bsum, NN);
    hipMemsetAsync(cursor, 0, NN * sizeof(unsigned), stream);
    k_scatter<<<gE, BLK, 0, stream>>>(src_u2, dst_u2, rp_u2, cursor, csr_u2, NE);

    // --- layer 1 ---
    k_gemm_in<<<gG, BLK, 0, stream>>>(x, W_in, A, NN);
    k_scale2<<<gN32, BLK, 0, stream>>>(A, dinv_u, dinv_u2, B, D, NN);
    k_pullv<HID, HID, true><<<gP32, BLK, 0, stream>>>(B, csr_u, rp_u, deg_u, dinv_u, b_in, C, NN);
    k_pullv<HID, HID, true><<<gP32, BLK, 0, stream>>>(D, csr_u2, rp_u2, deg_u2, dinv_u2, b_in, Ebuf, NN);
    k_mix<<<gN, BLK, 0, stream>>>(C, Ebuf, NN);

    // --- layer 2 ---
    k_gemm_hid<<<gG, BLK, 0, stream>>>(C, W_hid, dinv_u, A, NN);
    k_gemm_hid<<<gG, BLK, 0, stream>>>(Ebuf, W_hid, dinv_u2, B, NN);
    k_pullv<HID, HID, true><<<gP32, BLK, 0, stream>>>(A, csr_u, rp_u, deg_u, dinv_u, b_hid, C, NN);
    k_pullv<HID, HID, true><<<gP32, BLK, 0, stream>>>(B, csr_u2, rp_u2, deg_u2, dinv_u2, b_hid, Ebuf, NN);
    // mix + pack both branches scaled by dinv_u (layer 3 uses view u for BOTH)
    k_mix_pack<<<gN, BLK, 0, stream>>>(C, Ebuf, dinv_u, P, NN);

    // --- layer 3: one packed F=64 pull, then one fused GEMM ---
    k_pullv<64, 64, false><<<gP64, BLK, 0, stream>>>(P, csr_u, rp_u, deg_u, dinv_u, nullptr, Q, NN);
    k_gemm_out2<<<gG2, BLK, 0, stream>>>(Q, W_out, b_out, out, NN);

    (void)in_sizes; (void)n_in; (void)out_size; (void)ws_size;
}